// Round 3
// baseline (46.172 us; speedup 1.0000x reference)
//
#include <hip/hip_runtime.h>
#include <math.h>
#include <float.h>

#define B_ 32
#define N_ 256
#define T_OBS_ 50
#define T_S_ 25
#define D_ 128
#define D_H_ 256
#define P_ 8
#define R_ 4              // rows per block in fused kernel
#define NCH_ 16           // n-chunks in K1
#define NPC_ (N_ / NCH_)  // 16 n per chunk
#define PLANE_ (T_S_ * D_)  // 3200 floats per (b,n)

static constexpr double TWO_PI_D = 6.283185307179586476925286766559;
static constexpr float EPS_F = 1e-4f;

// ---------------------------------------------------------------------------
// K1: partial max over an n-chunk, contiguous streaming. grid = 32 b * 16
// chunks = 512 blocks (2/CU), 800 threads. Thread owns one float4 of the
// (t,d) plane; loops 16 n at 12.8 KB stride (block span 204.8 KB contiguous).
// ---------------------------------------------------------------------------
__global__ __launch_bounds__(800, 7) void k1_partial(
    const float* __restrict__ f_ego, const float* __restrict__ f_nei,
    float* __restrict__ part) {
  int b = blockIdx.x >> 4;
  int c = blockIdx.x & 15;
  int tid = threadIdx.x;  // 0..799
  int t = tid >> 5;
  int d4 = tid & 31;

  const float4 e =
      *(const float4*)(f_ego + ((size_t)b * T_S_ + t) * D_ + 4 * d4);
  const float* base =
      f_nei + ((size_t)b * N_ + (size_t)c * NPC_) * PLANE_ + 4 * tid;

  float4 m = make_float4(-FLT_MAX, -FLT_MAX, -FLT_MAX, -FLT_MAX);
#pragma unroll 8
  for (int i = 0; i < NPC_; ++i) {
    float4 v = *(const float4*)(base + (size_t)i * PLANE_);
    m.x = fmaxf(m.x, e.x * v.x);
    m.y = fmaxf(m.y, e.y * v.y);
    m.z = fmaxf(m.z, e.z * v.z);
    m.w = fmaxf(m.w, e.w * v.w);
  }
  *(float4*)(part + (size_t)blockIdx.x * PLANE_ + 4 * tid) = m;
}

// ---------------------------------------------------------------------------
// K2 helpers
// ---------------------------------------------------------------------------
__device__ __forceinline__ void stage_chunk(const float* __restrict__ src,
                                            float* dst, int tid) {
  // 64 KB = 4096 float4; 512 threads x 8. Linear lane-consecutive LDS dest.
  const float4* s4 = (const float4*)src;
  float4* d4 = (float4*)dst;
#pragma unroll
  for (int r = 0; r < 8; ++r) {
    int i = r * 512 + tid;
    __builtin_amdgcn_global_load_lds(
        (const __attribute__((address_space(1))) void*)(s4 + i),
        (__attribute__((address_space(3))) void*)(d4 + i), 16, 0, 0);
  }
}

// accumulate 64 k-steps: acc{0,1} += act{0,1}[k] * W[k][j], W chunk in LDS
__device__ __forceinline__ void accum_chunk(const float* act0,
                                            const float* act1,
                                            const float* wb, int j, float& a0,
                                            float& a1) {
#pragma unroll
  for (int kk = 0; kk < 64; kk += 4) {
    float4 x0 = *(const float4*)(act0 + kk);
    float4 x1 = *(const float4*)(act1 + kk);
    float w0 = wb[(kk + 0) * D_H_ + j];
    a0 = fmaf(x0.x, w0, a0);
    a1 = fmaf(x1.x, w0, a1);
    float w1 = wb[(kk + 1) * D_H_ + j];
    a0 = fmaf(x0.y, w1, a0);
    a1 = fmaf(x1.y, w1, a1);
    float w2 = wb[(kk + 2) * D_H_ + j];
    a0 = fmaf(x0.z, w2, a0);
    a1 = fmaf(x1.z, w2, a1);
    float w3 = wb[(kk + 3) * D_H_ + j];
    a0 = fmaf(x0.w, w3, a0);
    a1 = fmaf(x1.w, w3, a1);
  }
}

// ---------------------------------------------------------------------------
// K2: fused combine + MLP (LDS-staged weights, double-buffered 64 KB chunks)
// + polar histogram + output. 200 blocks x 512 threads, R_=4 rows/block.
// Chunk schedule: issue stage(c+1) -> compute(c) -> __syncthreads (vmcnt drain)
// ---------------------------------------------------------------------------
__global__ __launch_bounds__(512) void k2_fused(
    const float* __restrict__ part, const float* __restrict__ W1,
    const float* __restrict__ b1, const float* __restrict__ W2,
    const float* __restrict__ b2, const float* __restrict__ W3,
    const float* __restrict__ b3, const float* __restrict__ x_ego,
    const float* __restrict__ x_nei, const float* __restrict__ Wce,
    const float* __restrict__ bce, float* __restrict__ out) {
  __shared__ float wbuf[2][16384];   // 128 KB weight double-buffer
  __shared__ float sin_[R_][D_];     // 2 KB
  __shared__ float sh1[R_][D_H_];    // 4 KB
  __shared__ float sh2[R_][D_H_];    // 4 KB
  __shared__ float shp3[2][R_][64];  // 2 KB layer3 k-partials
  __shared__ float f3s[R_][64];      // 1 KB
  __shared__ float cnt[R_][P_], dsum[R_][P_], asum[R_][P_];

  const int tid = threadIdx.x;
  const int row0 = blockIdx.x * R_;

  stage_chunk(W1, wbuf[0], tid);  // c0 ASAP: DMA overlaps prologue

  if (tid < R_ * P_) {
    (&cnt[0][0])[tid] = 0.f;
    (&dsum[0][0])[tid] = 0.f;
    (&asum[0][0])[tid] = 0.f;
  }

  const int j = tid & 255;
  const int h = tid >> 8;  // row-pair selector
  const int r0 = 2 * h, r1 = 2 * h + 1;
  float bb1 = b1[j], bb2 = b2[j];
  float bb3 = b3[tid & 63];

  // ---- combine K1 partials -> sin_ ----
  {
    int r = tid >> 7, d = tid & 127;
    int row = row0 + r;
    int b = row / T_S_, t = row - b * T_S_;
    const float* p = part + (size_t)b * NCH_ * PLANE_ + t * D_ + d;
    float m = -FLT_MAX;
#pragma unroll
    for (int c = 0; c < NCH_; ++c) m = fmaxf(m, p[(size_t)c * PLANE_]);
    sin_[r][d] = m;
  }

  // ---- histogram input loads, hoisted early ----
  const int nh = tid & 255;
  float2 eg[2], xnv[2];
#pragma unroll
  for (int pp = 0; pp < 2; ++pp) {
    int r = h + 2 * pp;
    int row = row0 + r;
    int b = row / T_S_, t = row - b * T_S_;
    int tobs = 2 * t;
    eg[pp] = *(const float2*)&x_ego[((size_t)b * T_OBS_ + tobs) * 2];
    xnv[pp] = *(const float2*)&x_nei[(((size_t)b * N_ + nh) * T_OBS_ + tobs) * 2];
  }

  __syncthreads();  // B1: wbuf0=W1c0
  stage_chunk(W1 + 16384, wbuf[1], tid);
  float a10 = 0.f, a11 = 0.f;
  accum_chunk(&sin_[r0][0], &sin_[r1][0], wbuf[0], j, a10, a11);
  __syncthreads();  // B2: wbuf1=W1c1
  stage_chunk(W2, wbuf[0], tid);
  accum_chunk(&sin_[r0][64], &sin_[r1][64], wbuf[1], j, a10, a11);
  sh1[r0][j] = fmaxf(a10 + bb1, 0.f);
  sh1[r1][j] = fmaxf(a11 + bb1, 0.f);
  __syncthreads();  // B3: wbuf0=W2c0, sh1 ready
  stage_chunk(W2 + 16384, wbuf[1], tid);
  float a20 = 0.f, a21 = 0.f;
  accum_chunk(&sh1[r0][0], &sh1[r1][0], wbuf[0], j, a20, a21);
  __syncthreads();  // B4
  stage_chunk(W2 + 32768, wbuf[0], tid);
  accum_chunk(&sh1[r0][64], &sh1[r1][64], wbuf[1], j, a20, a21);
  __syncthreads();  // B5
  stage_chunk(W2 + 49152, wbuf[1], tid);
  accum_chunk(&sh1[r0][128], &sh1[r1][128], wbuf[0], j, a20, a21);
  __syncthreads();  // B6
  stage_chunk(W3, wbuf[0], tid);
  accum_chunk(&sh1[r0][192], &sh1[r1][192], wbuf[1], j, a20, a21);
  sh2[r0][j] = fmaxf(a20 + bb2, 0.f);
  sh2[r1][j] = fmaxf(a21 + bb2, 0.f);
  __syncthreads();  // B7: wbuf0=W3, sh2 ready

  // ---- layer 3: 256 -> 64, k-split 2-way ----
  {
    int j3 = tid & 63, r3 = (tid >> 6) & 3, h3 = tid >> 8;
    const float* wb = wbuf[0];
    float acc = 0.f;
#pragma unroll
    for (int kk = 0; kk < 128; kk += 4) {
      int k = h3 * 128 + kk;
      float4 x = *(const float4*)&sh2[r3][k];
      acc = fmaf(x.x, wb[(k + 0) * 64 + j3], acc);
      acc = fmaf(x.y, wb[(k + 1) * 64 + j3], acc);
      acc = fmaf(x.z, wb[(k + 2) * 64 + j3], acc);
      acc = fmaf(x.w, wb[(k + 3) * 64 + j3], acc);
    }
    shp3[h3][r3][j3] = acc;
  }

  // ---- histogram math + LDS atomics ----
#pragma unroll
  for (int pp = 0; pp < 2; ++pp) {
    int r = h + 2 * pp;
    float p0 = xnv[pp].x - eg[pp].x;
    float p1 = xnv[pp].y - eg[pp].y;
    float dist = sqrtf(p0 * p0 + p1 * p1);
    double angd = atan2((double)p0, (double)p1);
    if (angd < 0.0) angd += TWO_PI_D;
    float ang = (float)angd;
    int pidx = (int)(angd / (TWO_PI_D / (double)P_));
    bool mask = ((fabsf(p0) + fabsf(p1)) != 0.f) && (dist > 0.005f);
    if (mask && pidx >= 0 && pidx < P_) {
      atomicAdd(&cnt[r][pidx], 1.f);
      atomicAdd(&dsum[r][pidx], dist);
      atomicAdd(&asum[r][pidx], ang);
    }
  }
  __syncthreads();  // B8: shp3 + histogram done

  if (tid < 256) {
    int r = tid >> 6, j3 = tid & 63;
    f3s[r][j3] = fmaxf(shp3[0][r][j3] + shp3[1][r][j3] + bb3, 0.f);
  }
  __syncthreads();  // B9: f3s ready

  // ---- output: 4 rows x 1024 ----
  float* orow = out + (size_t)row0 * (P_ * D_);
#pragma unroll
  for (int ii = 0; ii < 8; ++ii) {
    int idx = tid + ii * 512;
    int r = idx >> 10;
    int i = idx & 1023;
    int p = i >> 7;
    int c = i & 127;
    float nn = cnt[r][p] + EPS_F;
    float val;
    if (c < 64) {
      val = f3s[r][c] * (cnt[r][p] / nn);
    } else {
      int jj = c - 64;
      val = fmaf(dsum[r][p] / nn, Wce[jj],
                 fmaf(asum[r][p] / nn, Wce[64 + jj], bce[jj]));
      val = fmaxf(val, 0.f);
    }
    orow[idx] = val;
  }
}

// ---------------------------------------------------------------------------
extern "C" void kernel_launch(void* const* d_in, const int* in_sizes, int n_in,
                              void* d_out, int out_size, void* d_ws,
                              size_t ws_size, hipStream_t stream) {
  const float* x_ego = (const float*)d_in[0];   // (32,50,2)
  const float* x_nei = (const float*)d_in[1];   // (32,256,50,2)
  const float* f_ego = (const float*)d_in[2];   // (32,25,128)
  const float* f_nei = (const float*)d_in[3];   // (32,256,25,128)
  const float* W1 = (const float*)d_in[4];      // (128,256)
  const float* b1 = (const float*)d_in[5];
  const float* W2 = (const float*)d_in[6];      // (256,256)
  const float* b2 = (const float*)d_in[7];
  const float* W3 = (const float*)d_in[8];      // (256,64)
  const float* b3 = (const float*)d_in[9];
  const float* Wce = (const float*)d_in[10];    // (2,64)
  const float* bce = (const float*)d_in[11];
  float* out = (float*)d_out;                   // (32,25,8,128)

  float* part = (float*)d_ws;  // 512 * 3200 floats = 6.55 MB

  k1_partial<<<B_ * NCH_, 800, 0, stream>>>(f_ego, f_nei, part);
  k2_fused<<<(B_ * T_S_) / R_, 512, 0, stream>>>(part, W1, b1, W2, b2, W3, b3,
                                                 x_ego, x_nei, Wce, bce, out);
}